// Round 1
// baseline (968.177 us; speedup 1.0000x reference)
//
#include <hip/hip_runtime.h>

#define NXg 432
#define NYg 496
#define SCELLS (NXg*NYg)   // 214272
#define PB 6000
#define NPTS 4096
#define DD 64
#define MM 1024
#define KK 4
#define BB 2
#define NROWS (PB*KK)      // 24000
#define NSEG 32
#define CHPTS (NPTS/NSEG)  // 128 points per segment
#define SHRINK_TH 0.0025f
#define BN_EPS 1e-3f
#define NEG_INF -3.402823466e38f

// sorted-descending top-4 insert on NAMED scalars; caller guarantees v > v3.
#define INS4(v, id, v0,v1,v2,v3, i0,i1,i2,i3) { \
    bool g0 = (v) > v0, g1 = (v) > v1, g2 = (v) > v2; \
    v3 = g2 ? v2 : (v);              i3 = g2 ? i2 : (id); \
    v2 = g2 ? (g1 ? v1 : (v)) : v2;  i2 = g2 ? (g1 ? i1 : (id)) : i2; \
    v1 = g1 ? (g0 ? v0 : (v)) : v1;  i1 = g1 ? (g0 ? i0 : (id)) : i1; \
    v0 = g0 ? (v) : v0;              i0 = g0 ? (id) : i0; \
}

// keep a float4's components pinned in VGPRs (defeats load-sinking/remat)
#define PIN4(a) asm volatile("" : "+v"(a.x), "+v"(a.y), "+v"(a.z), "+v"(a.w))

// ---------------- inverse map ----------------
__global__ __launch_bounds__(256) void k_init_inv(int* __restrict__ inv) {
    int i = blockIdx.x*256 + threadIdx.x;
    inv[i] = -1;
}

__global__ __launch_bounds__(256) void k_scatter_inv(const int* __restrict__ coords,
                                                     int* __restrict__ inv) {
    int i = blockIdx.x*256 + threadIdx.x;
    if (i >= BB*PB) return;
    int b = i / PB, p = i % PB;
    const int* c = coords + (size_t)i*3;
    int flat = c[0] + c[1]*NXg + c[2];
    inv[b*SCELLS + flat] = p;
}

// ---------------- score + top-4: lane = pillar, points via scalar loads ----------------
// grid (ceil(PB/256), BB, NSEG), block 256. Pillar row in 16 named float4 (VGPR),
// PINNED via empty asm so the allocator cannot sink the loads into the loop
// (previous build: VGPR_Count=44 < the 64 needed -> pillar re-loaded every iter,
// latency-bound at 57% VALUBusy). __launch_bounds__(256,4) raises the VGPR cap
// to 128 (4 waves/SIMD) so the pinned row + in-flight point data fit without spill.
// Point rows at wave-uniform addresses -> scalar/broadcast path; no LDS.
// Top-4 is lane-private: each lane sees every point of its 128-point chunk.
__global__ __launch_bounds__(256, 4) void k_score_topk(const float* __restrict__ pillars,
                                                       const float* __restrict__ points,
                                                       float* __restrict__ pV,
                                                       int* __restrict__ pI) {
    const int b = blockIdx.y;
    const int seg = blockIdx.z;
    const int t = threadIdx.x;
    const int pillar = blockIdx.x*256 + t;
    const int prow = pillar < PB ? pillar : PB-1;

    const float4* pil4 = (const float4*)(pillars + ((size_t)b*PB + prow)*DD);
    float4 p0=pil4[0],  p1=pil4[1],  p2=pil4[2],  p3=pil4[3],
           p4=pil4[4],  p5=pil4[5],  p6=pil4[6],  p7=pil4[7],
           p8=pil4[8],  p9=pil4[9],  p10=pil4[10], p11=pil4[11],
           p12=pil4[12], p13=pil4[13], p14=pil4[14], p15=pil4[15];
    PIN4(p0);  PIN4(p1);  PIN4(p2);  PIN4(p3);
    PIN4(p4);  PIN4(p5);  PIN4(p6);  PIN4(p7);
    PIN4(p8);  PIN4(p9);  PIN4(p10); PIN4(p11);
    PIN4(p12); PIN4(p13); PIN4(p14); PIN4(p15);

    float tv0=NEG_INF, tv1=NEG_INF, tv2=NEG_INF, tv3=NEG_INF;
    int   ti0=0, ti1=0, ti2=0, ti3=0;

    const float* ptsB = points + (size_t)b*NPTS*DD;
    const int j0 = seg*CHPTS, j1 = j0 + CHPTS;

    for (int j = j0; j < j1; j += 2) {
        const float4* q4 = (const float4*)(ptsB + (size_t)j*DD);   // wave-uniform addr
        float x0=0.f, x1=0.f, y0=0.f, y1=0.f;
#define DOT2(k, xa, ya) { float4 qa = q4[k]; float4 qb = q4[16+(k)]; \
        xa += p##k.x*qa.x + p##k.y*qa.y + p##k.z*qa.z + p##k.w*qa.w; \
        ya += p##k.x*qb.x + p##k.y*qb.y + p##k.z*qb.z + p##k.w*qb.w; }
        DOT2(0,x0,y0)  DOT2(1,x1,y1)  DOT2(2,x0,y0)  DOT2(3,x1,y1)
        DOT2(4,x0,y0)  DOT2(5,x1,y1)  DOT2(6,x0,y0)  DOT2(7,x1,y1)
        DOT2(8,x0,y0)  DOT2(9,x1,y1)  DOT2(10,x0,y0) DOT2(11,x1,y1)
        DOT2(12,x0,y0) DOT2(13,x1,y1) DOT2(14,x0,y0) DOT2(15,x1,y1)
#undef DOT2
        float v0 = x0 + x1, v1 = y0 + y1;
        if (v0 > tv3) INS4(v0, j,   tv0,tv1,tv2,tv3, ti0,ti1,ti2,ti3)
        if (v1 > tv3) INS4(v1, j+1, tv0,tv1,tv2,tv3, ti0,ti1,ti2,ti3)
    }

    if (pillar < PB) {
        size_t ob = (((size_t)b*NSEG + seg)*PB + pillar)*KK;
        pV[ob+0]=tv0; pV[ob+1]=tv1; pV[ob+2]=tv2; pV[ob+3]=tv3;
        pI[ob+0]=ti0; pI[ob+1]=ti1; pI[ob+2]=ti2; pI[ob+3]=ti3;
    }
}

// ---------------- merge NSEG partial top-4 lists ----------------
__global__ __launch_bounds__(256) void k_merge(const float* __restrict__ pV,
                                               const int* __restrict__ pI,
                                               int* __restrict__ idxOut) {
    int i = blockIdx.x*256 + threadIdx.x;
    if (i >= BB*PB) return;
    int b = i / PB, p = i % PB;
    float fv0=NEG_INF, fv1=NEG_INF, fv2=NEG_INF, fv3=NEG_INF;
    int fi0=0, fi1=0, fi2=0, fi3=0;
    for (int s = 0; s < NSEG; s++) {   // ascending seg = ascending point index
        size_t base = (((size_t)b*NSEG + s)*PB + p)*KK;
        #pragma unroll
        for (int q = 0; q < 4; q++) {
            float v = pV[base+q];
            if (v > fv3) INS4(v, pI[base+q], fv0,fv1,fv2,fv3, fi0,fi1,fi2,fi3)
        }
    }
    idxOut[(size_t)i*KK+0]=fi0; idxOut[(size_t)i*KK+1]=fi1;
    idxOut[(size_t)i*KK+2]=fi2; idxOut[(size_t)i*KK+3]=fi3;
}

// ---------------- logits GEMM: X[24000x64] @ memw^T[64x1024] ----------------
__global__ __launch_bounds__(256) void k_logits(const float* __restrict__ points,
                                                const int* __restrict__ idxIn,
                                                const float* __restrict__ memw,
                                                float* __restrict__ logits,
                                                int b) {
    __shared__ float4 sX4[64*16];
    __shared__ int sId[64];
    const int t = threadIdx.x;
    const int lane = t & 63, wv = t >> 6;
    const int row0 = blockIdx.x * 64;
    const int cg = blockIdx.y * 256 + wv * 64;

    if (t < 64) sId[t] = idxIn[(size_t)b*NROWS + row0 + t];

    const float4* mw4 = (const float4*)memw;
    float4 wreg[16];
    #pragma unroll
    for (int d4 = 0; d4 < 16; d4++) wreg[d4] = mw4[(size_t)(cg + lane)*16 + d4];

    __syncthreads();
    const float4* ptsB4 = (const float4*)(points + (size_t)b*NPTS*DD);
    for (int i = t; i < 1024; i += 256) {
        int r = i >> 4, c = i & 15;
        sX4[i] = ptsB4[(size_t)sId[r]*16 + c];
    }
    __syncthreads();

    for (int r = 0; r < 64; r += 2) {
        float a0 = 0.f, a1 = 0.f;
        #pragma unroll
        for (int d4 = 0; d4 < 16; d4++) {
            float4 x0 = sX4[r*16 + d4];
            float4 x1 = sX4[(r+1)*16 + d4];
            a0 += wreg[d4].x*x0.x + wreg[d4].y*x0.y + wreg[d4].z*x0.z + wreg[d4].w*x0.w;
            a1 += wreg[d4].x*x1.x + wreg[d4].y*x1.y + wreg[d4].z*x1.z + wreg[d4].w*x1.w;
        }
        logits[(size_t)(row0 + r)*MM + cg + lane] = a0;
        logits[(size_t)(row0 + r + 1)*MM + cg + lane] = a1;
    }
}

// ---------------- mem-unit: stats + att-on-the-fly GEMM + adapt ----------------
__global__ __launch_bounds__(256) void k_mo(const float* __restrict__ logits,
                                            const float* __restrict__ memw,
                                            const float* __restrict__ adaptw,
                                            float* __restrict__ hOut,
                                            int b) {
    __shared__ __align__(16) char smem[77824];
    float4* sAtt4 = (float4*)smem;              // [48][16] f4
    float4* sW4   = (float4*)(smem + 12288);    // [64 m][16 c4]
    float*  sWf   = (float*)sW4;
    __shared__ float sM[48], sRinv[48], sRsc[48];
    const int t = threadIdx.x;
    const int lane = t & 63, wv = t >> 6;
    const int p0 = blockIdx.x * 12;
    const int row0 = p0 * 4;

    const float4* lg4 = (const float4*)logits;
    #pragma unroll
    for (int rr = 0; rr < 12; rr++) {
        int r = wv*12 + rr;
        size_t base = (size_t)(row0 + r)*256;
        float4 l0 = lg4[base + lane];
        float4 l1 = lg4[base + 64 + lane];
        float4 l2 = lg4[base + 128 + lane];
        float4 l3 = lg4[base + 192 + lane];
        float m = fmaxf(fmaxf(fmaxf(l0.x,l0.y),fmaxf(l0.z,l0.w)),
                 fmaxf(fmaxf(fmaxf(l1.x,l1.y),fmaxf(l1.z,l1.w)),
                 fmaxf(fmaxf(fmaxf(l2.x,l2.y),fmaxf(l2.z,l2.w)),
                       fmaxf(fmaxf(l3.x,l3.y),fmaxf(l3.z,l3.w)))));
        #pragma unroll
        for (int off = 1; off < 64; off <<= 1) m = fmaxf(m, __shfl_xor(m, off));
        l0.x=__expf(l0.x-m); l0.y=__expf(l0.y-m); l0.z=__expf(l0.z-m); l0.w=__expf(l0.w-m);
        l1.x=__expf(l1.x-m); l1.y=__expf(l1.y-m); l1.z=__expf(l1.z-m); l1.w=__expf(l1.w-m);
        l2.x=__expf(l2.x-m); l2.y=__expf(l2.y-m); l2.z=__expf(l2.z-m); l2.w=__expf(l2.w-m);
        l3.x=__expf(l3.x-m); l3.y=__expf(l3.y-m); l3.z=__expf(l3.z-m); l3.w=__expf(l3.w-m);
        float s = (l0.x+l0.y+l0.z+l0.w) + (l1.x+l1.y+l1.z+l1.w)
                + (l2.x+l2.y+l2.z+l2.w) + (l3.x+l3.y+l3.z+l3.w);
        #pragma unroll
        for (int off = 1; off < 64; off <<= 1) s += __shfl_xor(s, off);
        float rinv = 1.f / s;
        float sh = 0.f;
        {
            float e, tt;
            e=l0.x*rinv; tt=e-SHRINK_TH; sh += tt>0.f ? e*tt/(tt+1e-12f) : 0.f;
            e=l0.y*rinv; tt=e-SHRINK_TH; sh += tt>0.f ? e*tt/(tt+1e-12f) : 0.f;
            e=l0.z*rinv; tt=e-SHRINK_TH; sh += tt>0.f ? e*tt/(tt+1e-12f) : 0.f;
            e=l0.w*rinv; tt=e-SHRINK_TH; sh += tt>0.f ? e*tt/(tt+1e-12f) : 0.f;
            e=l1.x*rinv; tt=e-SHRINK_TH; sh += tt>0.f ? e*tt/(tt+1e-12f) : 0.f;
            e=l1.y*rinv; tt=e-SHRINK_TH; sh += tt>0.f ? e*tt/(tt+1e-12f) : 0.f;
            e=l1.z*rinv; tt=e-SHRINK_TH; sh += tt>0.f ? e*tt/(tt+1e-12f) : 0.f;
            e=l1.w*rinv; tt=e-SHRINK_TH; sh += tt>0.f ? e*tt/(tt+1e-12f) : 0.f;
            e=l2.x*rinv; tt=e-SHRINK_TH; sh += tt>0.f ? e*tt/(tt+1e-12f) : 0.f;
            e=l2.y*rinv; tt=e-SHRINK_TH; sh += tt>0.f ? e*tt/(tt+1e-12f) : 0.f;
            e=l2.z*rinv; tt=e-SHRINK_TH; sh += tt>0.f ? e*tt/(tt+1e-12f) : 0.f;
            e=l2.w*rinv; tt=e-SHRINK_TH; sh += tt>0.f ? e*tt/(tt+1e-12f) : 0.f;
            e=l3.x*rinv; tt=e-SHRINK_TH; sh += tt>0.f ? e*tt/(tt+1e-12f) : 0.f;
            e=l3.y*rinv; tt=e-SHRINK_TH; sh += tt>0.f ? e*tt/(tt+1e-12f) : 0.f;
            e=l3.z*rinv; tt=e-SHRINK_TH; sh += tt>0.f ? e*tt/(tt+1e-12f) : 0.f;
            e=l3.w*rinv; tt=e-SHRINK_TH; sh += tt>0.f ? e*tt/(tt+1e-12f) : 0.f;
        }
        #pragma unroll
        for (int off = 1; off < 64; off <<= 1) sh += __shfl_xor(sh, off);
        if (lane == 0) { sM[r] = m; sRinv[r] = rinv; sRsc[r] = 1.f/(sh + 1e-12f); }
    }
    __syncthreads();

    float acc[12];
    #pragma unroll
    for (int s=0;s<12;s++) acc[s]=0.f;
    const float4* mw4 = (const float4*)memw;

    for (int tile = 0; tile < 16; tile++) {
        __syncthreads();
        for (int i = t; i < 768; i += 256) {
            int rr = i >> 4, m4 = i & 15;
            float4 lg = lg4[(size_t)(row0 + rr)*256 + tile*16 + m4];
            float m = sM[rr], rinv = sRinv[rr], rsc = sRsc[rr];
            float4 o;
            float e, tt;
            e=__expf(lg.x-m)*rinv; tt=e-SHRINK_TH; o.x = (tt>0.f ? e*tt/(tt+1e-12f) : 0.f)*rsc;
            e=__expf(lg.y-m)*rinv; tt=e-SHRINK_TH; o.y = (tt>0.f ? e*tt/(tt+1e-12f) : 0.f)*rsc;
            e=__expf(lg.z-m)*rinv; tt=e-SHRINK_TH; o.z = (tt>0.f ? e*tt/(tt+1e-12f) : 0.f)*rsc;
            e=__expf(lg.w-m)*rinv; tt=e-SHRINK_TH; o.w = (tt>0.f ? e*tt/(tt+1e-12f) : 0.f)*rsc;
            sAtt4[rr*16 + m4] = o;
        }
        #pragma unroll 4
        for (int i = t; i < 1024; i += 256) {
            int m = i >> 4, c4 = i & 15;
            sW4[m*16 + c4] = mw4[(size_t)(tile*64 + m)*16 + c4];
        }
        __syncthreads();
        #pragma unroll 4
        for (int m4 = 0; m4 < 16; m4++) {
            float w0 = sWf[(m4*4+0)*64 + lane];
            float w1 = sWf[(m4*4+1)*64 + lane];
            float w2 = sWf[(m4*4+2)*64 + lane];
            float w3 = sWf[(m4*4+3)*64 + lane];
            #pragma unroll
            for (int s = 0; s < 12; s++) {
                float4 a4 = sAtt4[(wv + 4*s)*16 + m4];
                acc[s] += a4.x*w0 + a4.y*w1 + a4.z*w2 + a4.w*w3;
            }
        }
    }
    __syncthreads();
    float* sMo = (float*)smem;
    float4* sA4 = (float4*)(smem + 12288);
    #pragma unroll
    for (int s = 0; s < 12; s++) {
        int r = wv + 4*s;
        sMo[r*64 + lane] = acc[s];
    }
    const float4* adG4 = (const float4*)adaptw;
    for (int i = t; i < 4096; i += 256) {
        int c = i >> 6, j4 = i & 63;
        sA4[c*64 + (j4 ^ (c & 15))] = adG4[c*64 + j4];
    }
    __syncthreads();
    const float4* sMo4 = (const float4*)sMo;
    float h0=0.f, h1=0.f, h2=0.f;
    #pragma unroll 8
    for (int j4 = 0; j4 < 64; j4++) {
        float4 a4 = sA4[lane*64 + (j4 ^ (lane & 15))];
        int sub = (j4 >> 4)*16 + (j4 & 15);
        float4 q0 = sMo4[(4*(wv+0))*16 + sub];
        float4 q1 = sMo4[(4*(wv+4))*16 + sub];
        float4 q2 = sMo4[(4*(wv+8))*16 + sub];
        h0 += q0.x*a4.x + q0.y*a4.y + q0.z*a4.z + q0.w*a4.w;
        h1 += q1.x*a4.x + q1.y*a4.y + q1.z*a4.z + q1.w*a4.w;
        h2 += q2.x*a4.x + q2.y*a4.y + q2.z*a4.z + q2.w*a4.w;
    }
    hOut[((size_t)b*PB + p0 + wv + 0)*DD + lane] = h0;
    hOut[((size_t)b*PB + p0 + wv + 4)*DD + lane] = h1;
    hOut[((size_t)b*PB + p0 + wv + 8)*DD + lane] = h2;
}

// ---------------- batchnorm stats, two-stage ----------------
__global__ __launch_bounds__(256) void k_bn1(const float* __restrict__ h,
                                             float* __restrict__ pSum,
                                             float* __restrict__ pSq) {
    const int bid = blockIdx.x;
    const int b = bid >> 5, ch = bid & 31;
    const int r0 = ch*188;
    int r1 = r0 + 188; if (r1 > PB) r1 = PB;
    __shared__ float sS[4*64], sS2[4*64];
    const int t = threadIdx.x;
    const int c = t & 63, stripe = t >> 6;
    float s = 0.f, s2 = 0.f;
    for (int r = r0 + stripe; r < r1; r += 4) {
        float v = h[((size_t)b*PB + r)*DD + c];
        s += v; s2 += v*v;
    }
    sS[stripe*64 + c] = s; sS2[stripe*64 + c] = s2;
    __syncthreads();
    if (t < 64) {
        float ts = sS[t] + sS[64+t] + sS[128+t] + sS[192+t];
        float ts2 = sS2[t] + sS2[64+t] + sS2[128+t] + sS2[192+t];
        pSum[(size_t)bid*64 + t] = ts;
        pSq[(size_t)bid*64 + t] = ts2;
    }
}

__global__ __launch_bounds__(64) void k_bn2(const float* __restrict__ pSum,
                                            const float* __restrict__ pSq,
                                            const float* __restrict__ gamma,
                                            float* __restrict__ bnMu,
                                            float* __restrict__ bnScale) {
    const int b = blockIdx.x;
    const int t = threadIdx.x;
    float ts = 0.f, ts2 = 0.f;
    for (int ch = 0; ch < 32; ch++) {
        ts += pSum[(size_t)(b*32 + ch)*64 + t];
        ts2 += pSq[(size_t)(b*32 + ch)*64 + t];
    }
    float mu = ts / (float)PB;
    float var = ts2 / (float)PB - mu*mu;
    if (var < 0.f) var = 0.f;
    bnMu[b*64+t] = mu;
    bnScale[b*64+t] = gamma[t] / sqrtf(var + BN_EPS);
}

// ---------------- dense fill (gather) ----------------
__global__ __launch_bounds__(256) void k_fill(const int* __restrict__ inv,
                                              const float* __restrict__ pillars,
                                              const float* __restrict__ h,
                                              const float* __restrict__ bnMu,
                                              const float* __restrict__ bnScale,
                                              const float* __restrict__ beta,
                                              float* __restrict__ out) {
    const int b = blockIdx.y;
    const int f = blockIdx.x*256 + threadIdx.x;
    __shared__ float sMu[64], sSc[64], sBe[64];
    if (threadIdx.x < 64) {
        sMu[threadIdx.x] = bnMu[b*64+threadIdx.x];
        sSc[threadIdx.x] = bnScale[b*64+threadIdx.x];
        sBe[threadIdx.x] = beta[threadIdx.x];
    }
    __syncthreads();
    int iv = inv[b*SCELLS + f];
    bool occ = iv >= 0;
    int iv0 = occ ? iv : 0;
    float* sp = out + (size_t)b*128*SCELLS;
    const float* prow = pillars + ((size_t)b*PB + iv0)*DD;
    const float* hrow = h + ((size_t)b*PB + iv0)*DD;
    #pragma unroll 4
    for (int c = 0; c < 64; c++)
        sp[(size_t)c*SCELLS + f] = occ ? prow[c] : 0.f;
    #pragma unroll 4
    for (int c = 0; c < 64; c++) {
        float v = 0.f;
        if (occ) {
            float hv = hrow[c];
            v = fmaxf((hv - sMu[c])*sSc[c] + sBe[c], 0.f);
        }
        sp[(size_t)(64+c)*SCELLS + f] = v;
    }
    float* pi = out + (size_t)BB*128*SCELLS + (size_t)b*3*SCELLS;
    pi[f]              = occ ? (float)(f / NXg) : 0.f;
    pi[SCELLS + f]     = occ ? (float)(f % NXg) : 0.f;
    pi[2*(size_t)SCELLS + f] = 0.f;
}

extern "C" void kernel_launch(void* const* d_in, const int* in_sizes, int n_in,
                              void* d_out, int out_size, void* d_ws, size_t ws_size,
                              hipStream_t stream) {
    const float* pillars = (const float*)d_in[0];
    const float* points  = (const float*)d_in[1];
    const int*   coords  = (const int*)d_in[2];
    const float* adaptw  = (const float*)d_in[3];
    const float* memw    = (const float*)d_in[4];
    const float* gamma   = (const float*)d_in[5];
    const float* beta    = (const float*)d_in[6];
    float* out = (float*)d_out;

    char* w = (char*)d_ws;
    int* inv = (int*)w;        w += (size_t)BB*SCELLS*4;
    int* idx = (int*)w;        w += (size_t)BB*PB*KK*4;
    float* h = (float*)w;      w += (size_t)BB*PB*DD*4;
    float* bnMu = (float*)w;   w += (size_t)BB*64*4;
    float* bnScale = (float*)w; w += (size_t)BB*64*4;
    float* pSum = (float*)w;   w += (size_t)BB*32*64*4;
    float* pSq = (float*)w;    w += (size_t)BB*32*64*4;
    float* logits = (float*)w;                    // 98.3 MB, per-batch reuse
    // pV/pI alias logits: score+merge fully complete (stream-ordered) before
    // k_logits writes this region. 2*32*6000*4*4B*2 = 12.3 MB << 98.3 MB.
    float* pV = logits;
    int*   pI = (int*)(logits + (size_t)BB*NSEG*PB*KK);

    k_init_inv<<<dim3(BB*SCELLS/256), dim3(256), 0, stream>>>(inv);
    k_scatter_inv<<<dim3((BB*PB+255)/256), dim3(256), 0, stream>>>(coords, inv);
    k_score_topk<<<dim3((PB+255)/256, BB, NSEG), dim3(256), 0, stream>>>(pillars, points, pV, pI);
    k_merge<<<dim3((BB*PB+255)/256), dim3(256), 0, stream>>>(pV, pI, idx);
    for (int b = 0; b < BB; b++) {
        k_logits<<<dim3(NROWS/64, 4), dim3(256), 0, stream>>>(points, idx, memw, logits, b);
        k_mo<<<dim3(PB/12), dim3(256), 0, stream>>>(logits, memw, adaptw, h, b);
    }
    k_bn1<<<dim3(BB*32), dim3(256), 0, stream>>>(h, pSum, pSq);
    k_bn2<<<dim3(BB), dim3(64), 0, stream>>>(pSum, pSq, gamma, bnMu, bnScale);
    k_fill<<<dim3(SCELLS/256, BB), dim3(256), 0, stream>>>(inv, pillars, h, bnMu, bnScale, beta, out);
}

// Round 2
// 954.375 us; speedup vs baseline: 1.0145x; 1.0145x over previous
//
#include <hip/hip_runtime.h>

#define NXg 432
#define NYg 496
#define SCELLS (NXg*NYg)   // 214272
#define PB 6000
#define NPTS 4096
#define DD 64
#define MM 1024
#define KK 4
#define BB 2
#define NROWS (PB*KK)      // 24000
#define NSEG 32
#define CHPTS (NPTS/NSEG)  // 128 points per segment
#define SHRINK_TH 0.0025f
#define BN_EPS 1e-3f
#define NEG_INF -3.402823466e38f

// sorted-descending top-4 insert on NAMED scalars; caller guarantees v > v3.
#define INS4(v, id, v0,v1,v2,v3, i0,i1,i2,i3) { \
    bool g0 = (v) > v0, g1 = (v) > v1, g2 = (v) > v2; \
    v3 = g2 ? v2 : (v);              i3 = g2 ? i2 : (id); \
    v2 = g2 ? (g1 ? v1 : (v)) : v2;  i2 = g2 ? (g1 ? i1 : (id)) : i2; \
    v1 = g1 ? (g0 ? v0 : (v)) : v1;  i1 = g1 ? (g0 ? i0 : (id)) : i1; \
    v0 = g0 ? (v) : v0;              i0 = g0 ? (id) : i0; \
}

// ---------------- inverse map ----------------
__global__ __launch_bounds__(256) void k_init_inv(int* __restrict__ inv) {
    int i = blockIdx.x*256 + threadIdx.x;
    inv[i] = -1;
}

__global__ __launch_bounds__(256) void k_scatter_inv(const int* __restrict__ coords,
                                                     int* __restrict__ inv) {
    int i = blockIdx.x*256 + threadIdx.x;
    if (i >= BB*PB) return;
    int b = i / PB, p = i % PB;
    const int* c = coords + (size_t)i*3;
    int flat = c[0] + c[1]*NXg + c[2];
    inv[b*SCELLS + flat] = p;
}

// ---------------- score + top-4 ----------------
// grid (ceil(PB/256), BB, NSEG), block 256, lane = pillar.
// Round-1 post-mortem: asm-pinning 64 pillar floats demoted them to scratch
// (VGPR stayed 44, VALUBusy 27%). This version fits the allocator's natural
// <=64-VGPR / 8-waves target instead of fighting it:
//   - 16-point groups with 16 named accumulators (fully unrolled -> registers)
//   - pillar row streamed in QUARTERS (4 float4 = 16 VGPRs live at a time),
//     reloaded per group from L1/L2 (16 loads per 1024 FMAs, ~3%)
//   - point addresses depend only on blockIdx.y/z + loop constants ->
//     block-uniform -> compiler emits s_load (SMEM pipe, free vs VALU)
// Peak live ~55 VGPR: no pressure, no load sinking, no spill.
__global__ __launch_bounds__(256) void k_score_topk(const float* __restrict__ pillars,
                                                    const float* __restrict__ points,
                                                    float* __restrict__ pV,
                                                    int* __restrict__ pI) {
    const int b = blockIdx.y;
    const int seg = blockIdx.z;
    const int t = threadIdx.x;
    const int pillar = blockIdx.x*256 + t;
    const int prow = pillar < PB ? pillar : PB-1;

    const float4* pil4 = (const float4*)(pillars + ((size_t)b*PB + prow)*DD);
    const float4* ptsB4 = (const float4*)(points + (size_t)b*NPTS*DD);

    float tv0=NEG_INF, tv1=NEG_INF, tv2=NEG_INF, tv3=NEG_INF;
    int   ti0=0, ti1=0, ti2=0, ti3=0;

    const int j0 = seg*CHPTS;

    for (int g = 0; g < CHPTS; g += 16) {
        const int jg = j0 + g;
        float acc[16];
        #pragma unroll
        for (int pt = 0; pt < 16; pt++) acc[pt] = 0.f;

        #pragma unroll 1
        for (int qtr = 0; qtr < 4; qtr++) {
            // 4 float4 of this lane's pillar row (16 VGPRs live)
            float4 w0 = pil4[qtr*4+0];
            float4 w1 = pil4[qtr*4+1];
            float4 w2 = pil4[qtr*4+2];
            float4 w3 = pil4[qtr*4+3];
            const float4* qb = ptsB4 + (size_t)jg*16 + qtr*4;  // block-uniform
            #pragma unroll
            for (int pt = 0; pt < 16; pt++) {
                float4 q0 = qb[pt*16 + 0];
                float4 q1 = qb[pt*16 + 1];
                float4 q2 = qb[pt*16 + 2];
                float4 q3 = qb[pt*16 + 3];
                acc[pt] += w0.x*q0.x + w0.y*q0.y + w0.z*q0.z + w0.w*q0.w
                         + w1.x*q1.x + w1.y*q1.y + w1.z*q1.z + w1.w*q1.w
                         + w2.x*q2.x + w2.y*q2.y + w2.z*q2.z + w2.w*q2.w
                         + w3.x*q3.x + w3.y*q3.y + w3.z*q3.z + w3.w*q3.w;
            }
        }

        // ascending point order preserves reference tie behavior
        #pragma unroll
        for (int pt = 0; pt < 16; pt++) {
            float v = acc[pt];
            if (v > tv3) INS4(v, jg + pt, tv0,tv1,tv2,tv3, ti0,ti1,ti2,ti3)
        }
    }

    if (pillar < PB) {
        size_t ob = (((size_t)b*NSEG + seg)*PB + pillar)*KK;
        pV[ob+0]=tv0; pV[ob+1]=tv1; pV[ob+2]=tv2; pV[ob+3]=tv3;
        pI[ob+0]=ti0; pI[ob+1]=ti1; pI[ob+2]=ti2; pI[ob+3]=ti3;
    }
}

// ---------------- merge NSEG partial top-4 lists ----------------
__global__ __launch_bounds__(256) void k_merge(const float* __restrict__ pV,
                                               const int* __restrict__ pI,
                                               int* __restrict__ idxOut) {
    int i = blockIdx.x*256 + threadIdx.x;
    if (i >= BB*PB) return;
    int b = i / PB, p = i % PB;
    float fv0=NEG_INF, fv1=NEG_INF, fv2=NEG_INF, fv3=NEG_INF;
    int fi0=0, fi1=0, fi2=0, fi3=0;
    for (int s = 0; s < NSEG; s++) {   // ascending seg = ascending point index
        size_t base = (((size_t)b*NSEG + s)*PB + p)*KK;
        #pragma unroll
        for (int q = 0; q < 4; q++) {
            float v = pV[base+q];
            if (v > fv3) INS4(v, pI[base+q], fv0,fv1,fv2,fv3, fi0,fi1,fi2,fi3)
        }
    }
    idxOut[(size_t)i*KK+0]=fi0; idxOut[(size_t)i*KK+1]=fi1;
    idxOut[(size_t)i*KK+2]=fi2; idxOut[(size_t)i*KK+3]=fi3;
}

// ---------------- logits GEMM: X[24000x64] @ memw^T[64x1024] ----------------
__global__ __launch_bounds__(256) void k_logits(const float* __restrict__ points,
                                                const int* __restrict__ idxIn,
                                                const float* __restrict__ memw,
                                                float* __restrict__ logits,
                                                int b) {
    __shared__ float4 sX4[64*16];
    __shared__ int sId[64];
    const int t = threadIdx.x;
    const int lane = t & 63, wv = t >> 6;
    const int row0 = blockIdx.x * 64;
    const int cg = blockIdx.y * 256 + wv * 64;

    if (t < 64) sId[t] = idxIn[(size_t)b*NROWS + row0 + t];

    const float4* mw4 = (const float4*)memw;
    float4 wreg[16];
    #pragma unroll
    for (int d4 = 0; d4 < 16; d4++) wreg[d4] = mw4[(size_t)(cg + lane)*16 + d4];

    __syncthreads();
    const float4* ptsB4 = (const float4*)(points + (size_t)b*NPTS*DD);
    for (int i = t; i < 1024; i += 256) {
        int r = i >> 4, c = i & 15;
        sX4[i] = ptsB4[(size_t)sId[r]*16 + c];
    }
    __syncthreads();

    for (int r = 0; r < 64; r += 2) {
        float a0 = 0.f, a1 = 0.f;
        #pragma unroll
        for (int d4 = 0; d4 < 16; d4++) {
            float4 x0 = sX4[r*16 + d4];
            float4 x1 = sX4[(r+1)*16 + d4];
            a0 += wreg[d4].x*x0.x + wreg[d4].y*x0.y + wreg[d4].z*x0.z + wreg[d4].w*x0.w;
            a1 += wreg[d4].x*x1.x + wreg[d4].y*x1.y + wreg[d4].z*x1.z + wreg[d4].w*x1.w;
        }
        logits[(size_t)(row0 + r)*MM + cg + lane] = a0;
        logits[(size_t)(row0 + r + 1)*MM + cg + lane] = a1;
    }
}

// ---------------- mem-unit: stats + att-on-the-fly GEMM + adapt ----------------
__global__ __launch_bounds__(256) void k_mo(const float* __restrict__ logits,
                                            const float* __restrict__ memw,
                                            const float* __restrict__ adaptw,
                                            float* __restrict__ hOut,
                                            int b) {
    __shared__ __align__(16) char smem[77824];
    float4* sAtt4 = (float4*)smem;              // [48][16] f4
    float4* sW4   = (float4*)(smem + 12288);    // [64 m][16 c4]
    float*  sWf   = (float*)sW4;
    __shared__ float sM[48], sRinv[48], sRsc[48];
    const int t = threadIdx.x;
    const int lane = t & 63, wv = t >> 6;
    const int p0 = blockIdx.x * 12;
    const int row0 = p0 * 4;

    const float4* lg4 = (const float4*)logits;
    #pragma unroll
    for (int rr = 0; rr < 12; rr++) {
        int r = wv*12 + rr;
        size_t base = (size_t)(row0 + r)*256;
        float4 l0 = lg4[base + lane];
        float4 l1 = lg4[base + 64 + lane];
        float4 l2 = lg4[base + 128 + lane];
        float4 l3 = lg4[base + 192 + lane];
        float m = fmaxf(fmaxf(fmaxf(l0.x,l0.y),fmaxf(l0.z,l0.w)),
                 fmaxf(fmaxf(fmaxf(l1.x,l1.y),fmaxf(l1.z,l1.w)),
                 fmaxf(fmaxf(fmaxf(l2.x,l2.y),fmaxf(l2.z,l2.w)),
                       fmaxf(fmaxf(l3.x,l3.y),fmaxf(l3.z,l3.w)))));
        #pragma unroll
        for (int off = 1; off < 64; off <<= 1) m = fmaxf(m, __shfl_xor(m, off));
        l0.x=__expf(l0.x-m); l0.y=__expf(l0.y-m); l0.z=__expf(l0.z-m); l0.w=__expf(l0.w-m);
        l1.x=__expf(l1.x-m); l1.y=__expf(l1.y-m); l1.z=__expf(l1.z-m); l1.w=__expf(l1.w-m);
        l2.x=__expf(l2.x-m); l2.y=__expf(l2.y-m); l2.z=__expf(l2.z-m); l2.w=__expf(l2.w-m);
        l3.x=__expf(l3.x-m); l3.y=__expf(l3.y-m); l3.z=__expf(l3.z-m); l3.w=__expf(l3.w-m);
        float s = (l0.x+l0.y+l0.z+l0.w) + (l1.x+l1.y+l1.z+l1.w)
                + (l2.x+l2.y+l2.z+l2.w) + (l3.x+l3.y+l3.z+l3.w);
        #pragma unroll
        for (int off = 1; off < 64; off <<= 1) s += __shfl_xor(s, off);
        float rinv = 1.f / s;
        float sh = 0.f;
        {
            float e, tt;
            e=l0.x*rinv; tt=e-SHRINK_TH; sh += tt>0.f ? e*tt/(tt+1e-12f) : 0.f;
            e=l0.y*rinv; tt=e-SHRINK_TH; sh += tt>0.f ? e*tt/(tt+1e-12f) : 0.f;
            e=l0.z*rinv; tt=e-SHRINK_TH; sh += tt>0.f ? e*tt/(tt+1e-12f) : 0.f;
            e=l0.w*rinv; tt=e-SHRINK_TH; sh += tt>0.f ? e*tt/(tt+1e-12f) : 0.f;
            e=l1.x*rinv; tt=e-SHRINK_TH; sh += tt>0.f ? e*tt/(tt+1e-12f) : 0.f;
            e=l1.y*rinv; tt=e-SHRINK_TH; sh += tt>0.f ? e*tt/(tt+1e-12f) : 0.f;
            e=l1.z*rinv; tt=e-SHRINK_TH; sh += tt>0.f ? e*tt/(tt+1e-12f) : 0.f;
            e=l1.w*rinv; tt=e-SHRINK_TH; sh += tt>0.f ? e*tt/(tt+1e-12f) : 0.f;
            e=l2.x*rinv; tt=e-SHRINK_TH; sh += tt>0.f ? e*tt/(tt+1e-12f) : 0.f;
            e=l2.y*rinv; tt=e-SHRINK_TH; sh += tt>0.f ? e*tt/(tt+1e-12f) : 0.f;
            e=l2.z*rinv; tt=e-SHRINK_TH; sh += tt>0.f ? e*tt/(tt+1e-12f) : 0.f;
            e=l2.w*rinv; tt=e-SHRINK_TH; sh += tt>0.f ? e*tt/(tt+1e-12f) : 0.f;
            e=l3.x*rinv; tt=e-SHRINK_TH; sh += tt>0.f ? e*tt/(tt+1e-12f) : 0.f;
            e=l3.y*rinv; tt=e-SHRINK_TH; sh += tt>0.f ? e*tt/(tt+1e-12f) : 0.f;
            e=l3.z*rinv; tt=e-SHRINK_TH; sh += tt>0.f ? e*tt/(tt+1e-12f) : 0.f;
            e=l3.w*rinv; tt=e-SHRINK_TH; sh += tt>0.f ? e*tt/(tt+1e-12f) : 0.f;
        }
        #pragma unroll
        for (int off = 1; off < 64; off <<= 1) sh += __shfl_xor(sh, off);
        if (lane == 0) { sM[r] = m; sRinv[r] = rinv; sRsc[r] = 1.f/(sh + 1e-12f); }
    }
    __syncthreads();

    float acc[12];
    #pragma unroll
    for (int s=0;s<12;s++) acc[s]=0.f;
    const float4* mw4 = (const float4*)memw;

    for (int tile = 0; tile < 16; tile++) {
        __syncthreads();
        for (int i = t; i < 768; i += 256) {
            int rr = i >> 4, m4 = i & 15;
            float4 lg = lg4[(size_t)(row0 + rr)*256 + tile*16 + m4];
            float m = sM[rr], rinv = sRinv[rr], rsc = sRsc[rr];
            float4 o;
            float e, tt;
            e=__expf(lg.x-m)*rinv; tt=e-SHRINK_TH; o.x = (tt>0.f ? e*tt/(tt+1e-12f) : 0.f)*rsc;
            e=__expf(lg.y-m)*rinv; tt=e-SHRINK_TH; o.y = (tt>0.f ? e*tt/(tt+1e-12f) : 0.f)*rsc;
            e=__expf(lg.z-m)*rinv; tt=e-SHRINK_TH; o.z = (tt>0.f ? e*tt/(tt+1e-12f) : 0.f)*rsc;
            e=__expf(lg.w-m)*rinv; tt=e-SHRINK_TH; o.w = (tt>0.f ? e*tt/(tt+1e-12f) : 0.f)*rsc;
            sAtt4[rr*16 + m4] = o;
        }
        #pragma unroll 4
        for (int i = t; i < 1024; i += 256) {
            int m = i >> 4, c4 = i & 15;
            sW4[m*16 + c4] = mw4[(size_t)(tile*64 + m)*16 + c4];
        }
        __syncthreads();
        #pragma unroll 4
        for (int m4 = 0; m4 < 16; m4++) {
            float w0 = sWf[(m4*4+0)*64 + lane];
            float w1 = sWf[(m4*4+1)*64 + lane];
            float w2 = sWf[(m4*4+2)*64 + lane];
            float w3 = sWf[(m4*4+3)*64 + lane];
            #pragma unroll
            for (int s = 0; s < 12; s++) {
                float4 a4 = sAtt4[(wv + 4*s)*16 + m4];
                acc[s] += a4.x*w0 + a4.y*w1 + a4.z*w2 + a4.w*w3;
            }
        }
    }
    __syncthreads();
    float* sMo = (float*)smem;
    float4* sA4 = (float4*)(smem + 12288);
    #pragma unroll
    for (int s = 0; s < 12; s++) {
        int r = wv + 4*s;
        sMo[r*64 + lane] = acc[s];
    }
    const float4* adG4 = (const float4*)adaptw;
    for (int i = t; i < 4096; i += 256) {
        int c = i >> 6, j4 = i & 63;
        sA4[c*64 + (j4 ^ (c & 15))] = adG4[c*64 + j4];
    }
    __syncthreads();
    const float4* sMo4 = (const float4*)sMo;
    float h0=0.f, h1=0.f, h2=0.f;
    #pragma unroll 8
    for (int j4 = 0; j4 < 64; j4++) {
        float4 a4 = sA4[lane*64 + (j4 ^ (lane & 15))];
        int sub = (j4 >> 4)*16 + (j4 & 15);
        float4 q0 = sMo4[(4*(wv+0))*16 + sub];
        float4 q1 = sMo4[(4*(wv+4))*16 + sub];
        float4 q2 = sMo4[(4*(wv+8))*16 + sub];
        h0 += q0.x*a4.x + q0.y*a4.y + q0.z*a4.z + q0.w*a4.w;
        h1 += q1.x*a4.x + q1.y*a4.y + q1.z*a4.z + q1.w*a4.w;
        h2 += q2.x*a4.x + q2.y*a4.y + q2.z*a4.z + q2.w*a4.w;
    }
    hOut[((size_t)b*PB + p0 + wv + 0)*DD + lane] = h0;
    hOut[((size_t)b*PB + p0 + wv + 4)*DD + lane] = h1;
    hOut[((size_t)b*PB + p0 + wv + 8)*DD + lane] = h2;
}

// ---------------- batchnorm stats, two-stage ----------------
__global__ __launch_bounds__(256) void k_bn1(const float* __restrict__ h,
                                             float* __restrict__ pSum,
                                             float* __restrict__ pSq) {
    const int bid = blockIdx.x;
    const int b = bid >> 5, ch = bid & 31;
    const int r0 = ch*188;
    int r1 = r0 + 188; if (r1 > PB) r1 = PB;
    __shared__ float sS[4*64], sS2[4*64];
    const int t = threadIdx.x;
    const int c = t & 63, stripe = t >> 6;
    float s = 0.f, s2 = 0.f;
    for (int r = r0 + stripe; r < r1; r += 4) {
        float v = h[((size_t)b*PB + r)*DD + c];
        s += v; s2 += v*v;
    }
    sS[stripe*64 + c] = s; sS2[stripe*64 + c] = s2;
    __syncthreads();
    if (t < 64) {
        float ts = sS[t] + sS[64+t] + sS[128+t] + sS[192+t];
        float ts2 = sS2[t] + sS2[64+t] + sS2[128+t] + sS2[192+t];
        pSum[(size_t)bid*64 + t] = ts;
        pSq[(size_t)bid*64 + t] = ts2;
    }
}

__global__ __launch_bounds__(64) void k_bn2(const float* __restrict__ pSum,
                                            const float* __restrict__ pSq,
                                            const float* __restrict__ gamma,
                                            float* __restrict__ bnMu,
                                            float* __restrict__ bnScale) {
    const int b = blockIdx.x;
    const int t = threadIdx.x;
    float ts = 0.f, ts2 = 0.f;
    for (int ch = 0; ch < 32; ch++) {
        ts += pSum[(size_t)(b*32 + ch)*64 + t];
        ts2 += pSq[(size_t)(b*32 + ch)*64 + t];
    }
    float mu = ts / (float)PB;
    float var = ts2 / (float)PB - mu*mu;
    if (var < 0.f) var = 0.f;
    bnMu[b*64+t] = mu;
    bnScale[b*64+t] = gamma[t] / sqrtf(var + BN_EPS);
}

// ---------------- dense fill (gather) ----------------
__global__ __launch_bounds__(256) void k_fill(const int* __restrict__ inv,
                                              const float* __restrict__ pillars,
                                              const float* __restrict__ h,
                                              const float* __restrict__ bnMu,
                                              const float* __restrict__ bnScale,
                                              const float* __restrict__ beta,
                                              float* __restrict__ out) {
    const int b = blockIdx.y;
    const int f = blockIdx.x*256 + threadIdx.x;
    __shared__ float sMu[64], sSc[64], sBe[64];
    if (threadIdx.x < 64) {
        sMu[threadIdx.x] = bnMu[b*64+threadIdx.x];
        sSc[threadIdx.x] = bnScale[b*64+threadIdx.x];
        sBe[threadIdx.x] = beta[threadIdx.x];
    }
    __syncthreads();
    int iv = inv[b*SCELLS + f];
    bool occ = iv >= 0;
    int iv0 = occ ? iv : 0;
    float* sp = out + (size_t)b*128*SCELLS;
    const float* prow = pillars + ((size_t)b*PB + iv0)*DD;
    const float* hrow = h + ((size_t)b*PB + iv0)*DD;
    #pragma unroll 4
    for (int c = 0; c < 64; c++)
        sp[(size_t)c*SCELLS + f] = occ ? prow[c] : 0.f;
    #pragma unroll 4
    for (int c = 0; c < 64; c++) {
        float v = 0.f;
        if (occ) {
            float hv = hrow[c];
            v = fmaxf((hv - sMu[c])*sSc[c] + sBe[c], 0.f);
        }
        sp[(size_t)(64+c)*SCELLS + f] = v;
    }
    float* pi = out + (size_t)BB*128*SCELLS + (size_t)b*3*SCELLS;
    pi[f]              = occ ? (float)(f / NXg) : 0.f;
    pi[SCELLS + f]     = occ ? (float)(f % NXg) : 0.f;
    pi[2*(size_t)SCELLS + f] = 0.f;
}

extern "C" void kernel_launch(void* const* d_in, const int* in_sizes, int n_in,
                              void* d_out, int out_size, void* d_ws, size_t ws_size,
                              hipStream_t stream) {
    const float* pillars = (const float*)d_in[0];
    const float* points  = (const float*)d_in[1];
    const int*   coords  = (const int*)d_in[2];
    const float* adaptw  = (const float*)d_in[3];
    const float* memw    = (const float*)d_in[4];
    const float* gamma   = (const float*)d_in[5];
    const float* beta    = (const float*)d_in[6];
    float* out = (float*)d_out;

    char* w = (char*)d_ws;
    int* inv = (int*)w;        w += (size_t)BB*SCELLS*4;
    int* idx = (int*)w;        w += (size_t)BB*PB*KK*4;
    float* h = (float*)w;      w += (size_t)BB*PB*DD*4;
    float* bnMu = (float*)w;   w += (size_t)BB*64*4;
    float* bnScale = (float*)w; w += (size_t)BB*64*4;
    float* pSum = (float*)w;   w += (size_t)BB*32*64*4;
    float* pSq = (float*)w;    w += (size_t)BB*32*64*4;
    float* logits = (float*)w;                    // 98.3 MB, per-batch reuse
    // pV/pI alias logits: score+merge fully complete (stream-ordered) before
    // k_logits writes this region. 2*32*6000*4*4B*2 = 12.3 MB << 98.3 MB.
    float* pV = logits;
    int*   pI = (int*)(logits + (size_t)BB*NSEG*PB*KK);

    k_init_inv<<<dim3(BB*SCELLS/256), dim3(256), 0, stream>>>(inv);
    k_scatter_inv<<<dim3((BB*PB+255)/256), dim3(256), 0, stream>>>(coords, inv);
    k_score_topk<<<dim3((PB+255)/256, BB, NSEG), dim3(256), 0, stream>>>(pillars, points, pV, pI);
    k_merge<<<dim3((BB*PB+255)/256), dim3(256), 0, stream>>>(pV, pI, idx);
    for (int b = 0; b < BB; b++) {
        k_logits<<<dim3(NROWS/64, 4), dim3(256), 0, stream>>>(points, idx, memw, logits, b);
        k_mo<<<dim3(PB/12), dim3(256), 0, stream>>>(logits, memw, adaptw, h, b);
    }
    k_bn1<<<dim3(BB*32), dim3(256), 0, stream>>>(h, pSum, pSq);
    k_bn2<<<dim3(BB), dim3(64), 0, stream>>>(pSum, pSq, gamma, bnMu, bnScale);
    k_fill<<<dim3(SCELLS/256, BB), dim3(256), 0, stream>>>(inv, pillars, h, bnMu, bnScale, beta, out);
}

// Round 3
// 858.992 us; speedup vs baseline: 1.1271x; 1.1110x over previous
//
#include <hip/hip_runtime.h>

#define NXg 432
#define NYg 496
#define SCELLS (NXg*NYg)   // 214272
#define PB 6000
#define NPTS 4096
#define DD 64
#define MM 1024
#define KK 4
#define BB 2
#define NROWS (PB*KK)      // 24000
#define NSEG 8
#define SEGPTS (NPTS/NSEG) // 512 points per segment
#define BM 64              // pillars per block
#define BN 64              // points per chunk
#define NCHUNK (SEGPTS/BN) // 8 chunks
#define NPBLK ((PB + BM - 1)/BM)  // 94 pillar blocks
#define SHRINK_TH 0.0025f
#define BN_EPS 1e-3f
#define NEG_INF -3.402823466e38f

// sorted-descending top-4 insert on NAMED scalars; caller guarantees v > v3.
// Within-thread scans are ascending-index, so strict > keeps earliest index on ties.
#define INS4(v, id, v0,v1,v2,v3, i0,i1,i2,i3) { \
    bool g0 = (v) > v0, g1 = (v) > v1, g2 = (v) > v2; \
    v3 = g2 ? v2 : (v);              i3 = g2 ? i2 : (id); \
    v2 = g2 ? (g1 ? v1 : (v)) : v2;  i2 = g2 ? (g1 ? i1 : (id)) : i2; \
    v1 = g1 ? (g0 ? v0 : (v)) : v1;  i1 = g1 ? (g0 ? i0 : (id)) : i1; \
    v0 = g0 ? (v) : v0;              i0 = g0 ? (id) : i0; \
}

// lexicographic (v desc, id asc) insert: order-independent merge of partial
// lists whose index ranges interleave. Matches top_k lowest-index-on-ties.
#define LEXGT(v,id,vk,ik) ((v) > (vk) || ((v) == (vk) && (id) < (ik)))
#define INS4L(v, id, v0,v1,v2,v3, i0,i1,i2,i3) { \
    if (LEXGT(v,id,v3,i3)) { \
        bool g0 = LEXGT(v,id,v0,i0), g1 = LEXGT(v,id,v1,i1), g2 = LEXGT(v,id,v2,i2); \
        v3 = g2 ? v2 : (v);              i3 = g2 ? i2 : (id); \
        v2 = g2 ? (g1 ? v1 : (v)) : v2;  i2 = g2 ? (g1 ? i1 : (id)) : i2; \
        v1 = g1 ? (g0 ? v0 : (v)) : v1;  i1 = g1 ? (g0 ? i0 : (id)) : i1; \
        v0 = g0 ? (v) : v0;              i0 = g0 ? (id) : i0; \
    } \
}

// ---------------- inverse map ----------------
__global__ __launch_bounds__(256) void k_init_inv(int* __restrict__ inv) {
    int i = blockIdx.x*256 + threadIdx.x;
    inv[i] = -1;
}

__global__ __launch_bounds__(256) void k_scatter_inv(const int* __restrict__ coords,
                                                     int* __restrict__ inv) {
    int i = blockIdx.x*256 + threadIdx.x;
    if (i >= BB*PB) return;
    int b = i / PB, p = i % PB;
    const int* c = coords + (size_t)i*3;
    int flat = c[0] + c[1]*NXg + c[2];
    inv[b*SCELLS + flat] = p;
}

// ---------------- score + top-4: LDS-tiled register-blocked GEMM ----------------
// Rounds 0-2 post-mortem: the lane=pillar + wave-uniform point-load structure is
// latency-bound on the SMEM/VMEM dependency chain (57% VALUBusy, 6x off the 41us
// fp32-VALU floor) regardless of register allocation. Canonical fix: tile both
// operands through LDS, register-block 4x4 per thread so 8 ds_read_b128 feed
// 64 FMAs (128 VALU cyc vs ~30 LDS cyc) -- VALU-bound by construction.
//   grid (94, BB, 8): block = 64 pillars x 512 points, 8 chunks of 64.
//   LDS: A[64][68] f32 (pad: 2-way banks), B[64][16] f4 XOR-swizzled (2-way),
//        scores[64][68] (region reused as merge scratch). 50 KB -> 3 blocks/CU.
//   Top-4: per chunk, scores go to LDS; thread t scans pillar t&63, points
//   (t>>6)*16..+15 (ascending). Block-end: 4 wave-partials per pillar merged
//   lexicographically (tie -> lowest index, order-independent).
__global__ __launch_bounds__(256) void k_score_topk(const float* __restrict__ pillars,
                                                    const float* __restrict__ points,
                                                    float* __restrict__ pV,
                                                    int* __restrict__ pI) {
    __shared__ __align__(16) char smem[51200];
    float4* sA4 = (float4*)smem;              // [64][17] f4  (17408 B)
    float4* sB4 = sA4 + 64*17;                // [64][16] f4, col^=(pt>>2)&15 (16384 B)
    float*  sS  = (float*)(sB4 + 64*16);      // [64][68] f32 (17408 B)

    const int b = blockIdx.y;
    const int seg = blockIdx.z;
    const int t = threadIdx.x;
    const int p0 = blockIdx.x * BM;
    const int j0 = seg * SEGPTS;

    const int rg = t >> 4;        // 16 row groups  (4 pillars each)
    const int cg = t & 15;        // 16 col groups  (4 points each)
    const int spil = t & 63;      // scan: pillar within tile
    const int ssub = t >> 6;      // scan: 16-point subrange (= wave id)

    const float4* pil4  = (const float4*)pillars;
    const float4* ptsB4 = (const float4*)(points + (size_t)b*NPTS*DD);

    // ---- stage A once (rows clamped for the 6000..6015 pad) ----
    #pragma unroll
    for (int q = 0; q < 4; q++) {
        int g = q*256 + t;
        int p = g >> 4, c4 = g & 15;
        int gp = p0 + p; if (gp > PB-1) gp = PB-1;
        sA4[p*17 + c4] = pil4[((size_t)b*PB + gp)*16 + c4];
    }
    // ---- stage B chunk 0 ----
    {
        const float4* src = ptsB4 + (size_t)j0*16;
        #pragma unroll
        for (int q = 0; q < 4; q++) {
            int g = q*256 + t;
            int pt = g >> 4, c4 = g & 15;
            sB4[pt*16 + (c4 ^ ((pt >> 2) & 15))] = src[g];
        }
    }

    float tv0=NEG_INF, tv1=NEG_INF, tv2=NEG_INF, tv3=NEG_INF;
    int   ti0=0, ti1=0, ti2=0, ti3=0;

    __syncthreads();

    for (int c = 0; c < NCHUNK; c++) {
        // ---- GEMM: 4 pillars x 4 points x 64 k per thread ----
        float acc[4][4];
        #pragma unroll
        for (int i = 0; i < 4; i++)
            #pragma unroll
            for (int j = 0; j < 4; j++) acc[i][j] = 0.f;

        #pragma unroll
        for (int k4 = 0; k4 < 16; k4++) {
            float4 aR[4], bR[4];
            #pragma unroll
            for (int i = 0; i < 4; i++) aR[i] = sA4[(rg*4+i)*17 + k4];
            #pragma unroll
            for (int j = 0; j < 4; j++) bR[j] = sB4[(cg*4+j)*16 + (k4 ^ cg)];
            #pragma unroll
            for (int i = 0; i < 4; i++)
                #pragma unroll
                for (int j = 0; j < 4; j++)
                    acc[i][j] += aR[i].x*bR[j].x + aR[i].y*bR[j].y
                               + aR[i].z*bR[j].z + aR[i].w*bR[j].w;
        }
        __syncthreads();   // B(c) fully consumed; scores region free

        // ---- scores -> LDS ----
        #pragma unroll
        for (int i = 0; i < 4; i++)
            *(float4*)(sS + (rg*4+i)*68 + cg*4) =
                make_float4(acc[i][0], acc[i][1], acc[i][2], acc[i][3]);
        // ---- stage B chunk c+1 (overlaps with scan after barrier) ----
        if (c+1 < NCHUNK) {
            const float4* src = ptsB4 + (size_t)(j0 + (c+1)*BN)*16;
            #pragma unroll
            for (int q = 0; q < 4; q++) {
                int g = q*256 + t;
                int pt = g >> 4, c4 = g & 15;
                sB4[pt*16 + (c4 ^ ((pt >> 2) & 15))] = src[g];
            }
        }
        __syncthreads();   // scores(c) visible, B(c+1) staged

        // ---- scan: 16 points of one pillar row, ascending ----
        {
            const float4* sr = (const float4*)(sS + spil*68) + ssub*4;
            int ib = j0 + c*BN + ssub*16;
            #pragma unroll
            for (int q = 0; q < 4; q++) {
                float4 v = sr[q];
                if (v.x > tv3) INS4(v.x, ib+q*4+0, tv0,tv1,tv2,tv3, ti0,ti1,ti2,ti3)
                if (v.y > tv3) INS4(v.y, ib+q*4+1, tv0,tv1,tv2,tv3, ti0,ti1,ti2,ti3)
                if (v.z > tv3) INS4(v.z, ib+q*4+2, tv0,tv1,tv2,tv3, ti0,ti1,ti2,ti3)
                if (v.w > tv3) INS4(v.w, ib+q*4+3, tv0,tv1,tv2,tv3, ti0,ti1,ti2,ti3)
            }
        }
        // next GEMM reads B(c+1): staged before the barrier above; scores(c+1)
        // writes happen only after the post-GEMM barrier, when all scans done.
    }

    __syncthreads();   // all scans done before scratch overwrites scores region
    // ---- merge 4 wave-partials per pillar (lexicographic) ----
    float* vS = sS;                 // [3][64][4] values
    int*   iS = (int*)(sS + 768);   // [3][64][4] indices
    if (t >= 64) {
        int base = ((ssub-1)*64 + spil)*4;
        vS[base+0]=tv0; vS[base+1]=tv1; vS[base+2]=tv2; vS[base+3]=tv3;
        iS[base+0]=ti0; iS[base+1]=ti1; iS[base+2]=ti2; iS[base+3]=ti3;
    }
    __syncthreads();
    if (t < 64) {
        #pragma unroll
        for (int s = 0; s < 3; s++) {
            int base = (s*64 + t)*4;
            #pragma unroll
            for (int q = 0; q < 4; q++) {
                float v = vS[base+q];
                int id = iS[base+q];
                INS4L(v, id, tv0,tv1,tv2,tv3, ti0,ti1,ti2,ti3)
            }
        }
        if (p0 + t < PB) {
            size_t ob = (((size_t)b*NSEG + seg)*PB + (p0 + t))*KK;
            pV[ob+0]=tv0; pV[ob+1]=tv1; pV[ob+2]=tv2; pV[ob+3]=tv3;
            pI[ob+0]=ti0; pI[ob+1]=ti1; pI[ob+2]=ti2; pI[ob+3]=ti3;
        }
    }
}

// ---------------- merge NSEG partial top-4 lists ----------------
__global__ __launch_bounds__(256) void k_merge(const float* __restrict__ pV,
                                               const int* __restrict__ pI,
                                               int* __restrict__ idxOut) {
    int i = blockIdx.x*256 + threadIdx.x;
    if (i >= BB*PB) return;
    int b = i / PB, p = i % PB;
    float fv0=NEG_INF, fv1=NEG_INF, fv2=NEG_INF, fv3=NEG_INF;
    int fi0=0, fi1=0, fi2=0, fi3=0;
    for (int s = 0; s < NSEG; s++) {   // ascending seg = ascending point ranges
        size_t base = (((size_t)b*NSEG + s)*PB + p)*KK;
        #pragma unroll
        for (int q = 0; q < 4; q++) {
            float v = pV[base+q];
            if (v > fv3) INS4(v, pI[base+q], fv0,fv1,fv2,fv3, fi0,fi1,fi2,fi3)
        }
    }
    idxOut[(size_t)i*KK+0]=fi0; idxOut[(size_t)i*KK+1]=fi1;
    idxOut[(size_t)i*KK+2]=fi2; idxOut[(size_t)i*KK+3]=fi3;
}

// ---------------- logits GEMM: X[24000x64] @ memw^T[64x1024] ----------------
__global__ __launch_bounds__(256) void k_logits(const float* __restrict__ points,
                                                const int* __restrict__ idxIn,
                                                const float* __restrict__ memw,
                                                float* __restrict__ logits,
                                                int b) {
    __shared__ float4 sX4[64*16];
    __shared__ int sId[64];
    const int t = threadIdx.x;
    const int lane = t & 63, wv = t >> 6;
    const int row0 = blockIdx.x * 64;
    const int cg = blockIdx.y * 256 + wv * 64;

    if (t < 64) sId[t] = idxIn[(size_t)b*NROWS + row0 + t];

    const float4* mw4 = (const float4*)memw;
    float4 wreg[16];
    #pragma unroll
    for (int d4 = 0; d4 < 16; d4++) wreg[d4] = mw4[(size_t)(cg + lane)*16 + d4];

    __syncthreads();
    const float4* ptsB4 = (const float4*)(points + (size_t)b*NPTS*DD);
    for (int i = t; i < 1024; i += 256) {
        int r = i >> 4, c = i & 15;
        sX4[i] = ptsB4[(size_t)sId[r]*16 + c];
    }
    __syncthreads();

    for (int r = 0; r < 64; r += 2) {
        float a0 = 0.f, a1 = 0.f;
        #pragma unroll
        for (int d4 = 0; d4 < 16; d4++) {
            float4 x0 = sX4[r*16 + d4];
            float4 x1 = sX4[(r+1)*16 + d4];
            a0 += wreg[d4].x*x0.x + wreg[d4].y*x0.y + wreg[d4].z*x0.z + wreg[d4].w*x0.w;
            a1 += wreg[d4].x*x1.x + wreg[d4].y*x1.y + wreg[d4].z*x1.z + wreg[d4].w*x1.w;
        }
        logits[(size_t)(row0 + r)*MM + cg + lane] = a0;
        logits[(size_t)(row0 + r + 1)*MM + cg + lane] = a1;
    }
}

// ---------------- mem-unit: stats + att-on-the-fly GEMM + adapt ----------------
__global__ __launch_bounds__(256) void k_mo(const float* __restrict__ logits,
                                            const float* __restrict__ memw,
                                            const float* __restrict__ adaptw,
                                            float* __restrict__ hOut,
                                            int b) {
    __shared__ __align__(16) char smem[77824];
    float4* sAtt4 = (float4*)smem;              // [48][16] f4
    float4* sW4   = (float4*)(smem + 12288);    // [64 m][16 c4]
    float*  sWf   = (float*)sW4;
    __shared__ float sM[48], sRinv[48], sRsc[48];
    const int t = threadIdx.x;
    const int lane = t & 63, wv = t >> 6;
    const int p0 = blockIdx.x * 12;
    const int row0 = p0 * 4;

    const float4* lg4 = (const float4*)logits;
    #pragma unroll
    for (int rr = 0; rr < 12; rr++) {
        int r = wv*12 + rr;
        size_t base = (size_t)(row0 + r)*256;
        float4 l0 = lg4[base + lane];
        float4 l1 = lg4[base + 64 + lane];
        float4 l2 = lg4[base + 128 + lane];
        float4 l3 = lg4[base + 192 + lane];
        float m = fmaxf(fmaxf(fmaxf(l0.x,l0.y),fmaxf(l0.z,l0.w)),
                 fmaxf(fmaxf(fmaxf(l1.x,l1.y),fmaxf(l1.z,l1.w)),
                 fmaxf(fmaxf(fmaxf(l2.x,l2.y),fmaxf(l2.z,l2.w)),
                       fmaxf(fmaxf(l3.x,l3.y),fmaxf(l3.z,l3.w)))));
        #pragma unroll
        for (int off = 1; off < 64; off <<= 1) m = fmaxf(m, __shfl_xor(m, off));
        l0.x=__expf(l0.x-m); l0.y=__expf(l0.y-m); l0.z=__expf(l0.z-m); l0.w=__expf(l0.w-m);
        l1.x=__expf(l1.x-m); l1.y=__expf(l1.y-m); l1.z=__expf(l1.z-m); l1.w=__expf(l1.w-m);
        l2.x=__expf(l2.x-m); l2.y=__expf(l2.y-m); l2.z=__expf(l2.z-m); l2.w=__expf(l2.w-m);
        l3.x=__expf(l3.x-m); l3.y=__expf(l3.y-m); l3.z=__expf(l3.z-m); l3.w=__expf(l3.w-m);
        float s = (l0.x+l0.y+l0.z+l0.w) + (l1.x+l1.y+l1.z+l1.w)
                + (l2.x+l2.y+l2.z+l2.w) + (l3.x+l3.y+l3.z+l3.w);
        #pragma unroll
        for (int off = 1; off < 64; off <<= 1) s += __shfl_xor(s, off);
        float rinv = 1.f / s;
        float sh = 0.f;
        {
            float e, tt;
            e=l0.x*rinv; tt=e-SHRINK_TH; sh += tt>0.f ? e*tt/(tt+1e-12f) : 0.f;
            e=l0.y*rinv; tt=e-SHRINK_TH; sh += tt>0.f ? e*tt/(tt+1e-12f) : 0.f;
            e=l0.z*rinv; tt=e-SHRINK_TH; sh += tt>0.f ? e*tt/(tt+1e-12f) : 0.f;
            e=l0.w*rinv; tt=e-SHRINK_TH; sh += tt>0.f ? e*tt/(tt+1e-12f) : 0.f;
            e=l1.x*rinv; tt=e-SHRINK_TH; sh += tt>0.f ? e*tt/(tt+1e-12f) : 0.f;
            e=l1.y*rinv; tt=e-SHRINK_TH; sh += tt>0.f ? e*tt/(tt+1e-12f) : 0.f;
            e=l1.z*rinv; tt=e-SHRINK_TH; sh += tt>0.f ? e*tt/(tt+1e-12f) : 0.f;
            e=l1.w*rinv; tt=e-SHRINK_TH; sh += tt>0.f ? e*tt/(tt+1e-12f) : 0.f;
            e=l2.x*rinv; tt=e-SHRINK_TH; sh += tt>0.f ? e*tt/(tt+1e-12f) : 0.f;
            e=l2.y*rinv; tt=e-SHRINK_TH; sh += tt>0.f ? e*tt/(tt+1e-12f) : 0.f;
            e=l2.z*rinv; tt=e-SHRINK_TH; sh += tt>0.f ? e*tt/(tt+1e-12f) : 0.f;
            e=l2.w*rinv; tt=e-SHRINK_TH; sh += tt>0.f ? e*tt/(tt+1e-12f) : 0.f;
            e=l3.x*rinv; tt=e-SHRINK_TH; sh += tt>0.f ? e*tt/(tt+1e-12f) : 0.f;
            e=l3.y*rinv; tt=e-SHRINK_TH; sh += tt>0.f ? e*tt/(tt+1e-12f) : 0.f;
            e=l3.z*rinv; tt=e-SHRINK_TH; sh += tt>0.f ? e*tt/(tt+1e-12f) : 0.f;
            e=l3.w*rinv; tt=e-SHRINK_TH; sh += tt>0.f ? e*tt/(tt+1e-12f) : 0.f;
        }
        #pragma unroll
        for (int off = 1; off < 64; off <<= 1) sh += __shfl_xor(sh, off);
        if (lane == 0) { sM[r] = m; sRinv[r] = rinv; sRsc[r] = 1.f/(sh + 1e-12f); }
    }
    __syncthreads();

    float acc[12];
    #pragma unroll
    for (int s=0;s<12;s++) acc[s]=0.f;
    const float4* mw4 = (const float4*)memw;

    for (int tile = 0; tile < 16; tile++) {
        __syncthreads();
        for (int i = t; i < 768; i += 256) {
            int rr = i >> 4, m4 = i & 15;
            float4 lg = lg4[(size_t)(row0 + rr)*256 + tile*16 + m4];
            float m = sM[rr], rinv = sRinv[rr], rsc = sRsc[rr];
            float4 o;
            float e, tt;
            e=__expf(lg.x-m)*rinv; tt=e-SHRINK_TH; o.x = (tt>0.f ? e*tt/(tt+1e-12f) : 0.f)*rsc;
            e=__expf(lg.y-m)*rinv; tt=e-SHRINK_TH; o.y = (tt>0.f ? e*tt/(tt+1e-12f) : 0.f)*rsc;
            e=__expf(lg.z-m)*rinv; tt=e-SHRINK_TH; o.z = (tt>0.f ? e*tt/(tt+1e-12f) : 0.f)*rsc;
            e=__expf(lg.w-m)*rinv; tt=e-SHRINK_TH; o.w = (tt>0.f ? e*tt/(tt+1e-12f) : 0.f)*rsc;
            sAtt4[rr*16 + m4] = o;
        }
        #pragma unroll 4
        for (int i = t; i < 1024; i += 256) {
            int m = i >> 4, c4 = i & 15;
            sW4[m*16 + c4] = mw4[(size_t)(tile*64 + m)*16 + c4];
        }
        __syncthreads();
        #pragma unroll 4
        for (int m4 = 0; m4 < 16; m4++) {
            float w0 = sWf[(m4*4+0)*64 + lane];
            float w1 = sWf[(m4*4+1)*64 + lane];
            float w2 = sWf[(m4*4+2)*64 + lane];
            float w3 = sWf[(m4*4+3)*64 + lane];
            #pragma unroll
            for (int s = 0; s < 12; s++) {
                float4 a4 = sAtt4[(wv + 4*s)*16 + m4];
                acc[s] += a4.x*w0 + a4.y*w1 + a4.z*w2 + a4.w*w3;
            }
        }
    }
    __syncthreads();
    float* sMo = (float*)smem;
    float4* sA4 = (float4*)(smem + 12288);
    #pragma unroll
    for (int s = 0; s < 12; s++) {
        int r = wv + 4*s;
        sMo[r*64 + lane] = acc[s];
    }
    const float4* adG4 = (const float4*)adaptw;
    for (int i = t; i < 4096; i += 256) {
        int c = i >> 6, j4 = i & 63;
        sA4[c*64 + (j4 ^ (c & 15))] = adG4[c*64 + j4];
    }
    __syncthreads();
    const float4* sMo4 = (const float4*)sMo;
    float h0=0.f, h1=0.f, h2=0.f;
    #pragma unroll 8
    for (int j4 = 0; j4 < 64; j4++) {
        float4 a4 = sA4[lane*64 + (j4 ^ (lane & 15))];
        int sub = (j4 >> 4)*16 + (j4 & 15);
        float4 q0 = sMo4[(4*(wv+0))*16 + sub];
        float4 q1 = sMo4[(4*(wv+4))*16 + sub];
        float4 q2 = sMo4[(4*(wv+8))*16 + sub];
        h0 += q0.x*a4.x + q0.y*a4.y + q0.z*a4.z + q0.w*a4.w;
        h1 += q1.x*a4.x + q1.y*a4.y + q1.z*a4.z + q1.w*a4.w;
        h2 += q2.x*a4.x + q2.y*a4.y + q2.z*a4.z + q2.w*a4.w;
    }
    hOut[((size_t)b*PB + p0 + wv + 0)*DD + lane] = h0;
    hOut[((size_t)b*PB + p0 + wv + 4)*DD + lane] = h1;
    hOut[((size_t)b*PB + p0 + wv + 8)*DD + lane] = h2;
}

// ---------------- batchnorm stats, two-stage ----------------
__global__ __launch_bounds__(256) void k_bn1(const float* __restrict__ h,
                                             float* __restrict__ pSum,
                                             float* __restrict__ pSq) {
    const int bid = blockIdx.x;
    const int b = bid >> 5, ch = bid & 31;
    const int r0 = ch*188;
    int r1 = r0 + 188; if (r1 > PB) r1 = PB;
    __shared__ float sS[4*64], sS2[4*64];
    const int t = threadIdx.x;
    const int c = t & 63, stripe = t >> 6;
    float s = 0.f, s2 = 0.f;
    for (int r = r0 + stripe; r < r1; r += 4) {
        float v = h[((size_t)b*PB + r)*DD + c];
        s += v; s2 += v*v;
    }
    sS[stripe*64 + c] = s; sS2[stripe*64 + c] = s2;
    __syncthreads();
    if (t < 64) {
        float ts = sS[t] + sS[64+t] + sS[128+t] + sS[192+t];
        float ts2 = sS2[t] + sS2[64+t] + sS2[128+t] + sS2[192+t];
        pSum[(size_t)bid*64 + t] = ts;
        pSq[(size_t)bid*64 + t] = ts2;
    }
}

__global__ __launch_bounds__(64) void k_bn2(const float* __restrict__ pSum,
                                            const float* __restrict__ pSq,
                                            const float* __restrict__ gamma,
                                            float* __restrict__ bnMu,
                                            float* __restrict__ bnScale) {
    const int b = blockIdx.x;
    const int t = threadIdx.x;
    float ts = 0.f, ts2 = 0.f;
    for (int ch = 0; ch < 32; ch++) {
        ts += pSum[(size_t)(b*32 + ch)*64 + t];
        ts2 += pSq[(size_t)(b*32 + ch)*64 + t];
    }
    float mu = ts / (float)PB;
    float var = ts2 / (float)PB - mu*mu;
    if (var < 0.f) var = 0.f;
    bnMu[b*64+t] = mu;
    bnScale[b*64+t] = gamma[t] / sqrtf(var + BN_EPS);
}

// ---------------- dense fill (gather) ----------------
__global__ __launch_bounds__(256) void k_fill(const int* __restrict__ inv,
                                              const float* __restrict__ pillars,
                                              const float* __restrict__ h,
                                              const float* __restrict__ bnMu,
                                              const float* __restrict__ bnScale,
                                              const float* __restrict__ beta,
                                              float* __restrict__ out) {
    const int b = blockIdx.y;
    const int f = blockIdx.x*256 + threadIdx.x;
    __shared__ float sMu[64], sSc[64], sBe[64];
    if (threadIdx.x < 64) {
        sMu[threadIdx.x] = bnMu[b*64+threadIdx.x];
        sSc[threadIdx.x] = bnScale[b*64+threadIdx.x];
        sBe[threadIdx.x] = beta[threadIdx.x];
    }
    __syncthreads();
    int iv = inv[b*SCELLS + f];
    bool occ = iv >= 0;
    int iv0 = occ ? iv : 0;
    float* sp = out + (size_t)b*128*SCELLS;
    const float* prow = pillars + ((size_t)b*PB + iv0)*DD;
    const float* hrow = h + ((size_t)b*PB + iv0)*DD;
    #pragma unroll 4
    for (int c = 0; c < 64; c++)
        sp[(size_t)c*SCELLS + f] = occ ? prow[c] : 0.f;
    #pragma unroll 4
    for (int c = 0; c < 64; c++) {
        float v = 0.f;
        if (occ) {
            float hv = hrow[c];
            v = fmaxf((hv - sMu[c])*sSc[c] + sBe[c], 0.f);
        }
        sp[(size_t)(64+c)*SCELLS + f] = v;
    }
    float* pi = out + (size_t)BB*128*SCELLS + (size_t)b*3*SCELLS;
    pi[f]              = occ ? (float)(f / NXg) : 0.f;
    pi[SCELLS + f]     = occ ? (float)(f % NXg) : 0.f;
    pi[2*(size_t)SCELLS + f] = 0.f;
}

extern "C" void kernel_launch(void* const* d_in, const int* in_sizes, int n_in,
                              void* d_out, int out_size, void* d_ws, size_t ws_size,
                              hipStream_t stream) {
    const float* pillars = (const float*)d_in[0];
    const float* points  = (const float*)d_in[1];
    const int*   coords  = (const int*)d_in[2];
    const float* adaptw  = (const float*)d_in[3];
    const float* memw    = (const float*)d_in[4];
    const float* gamma   = (const float*)d_in[5];
    const float* beta    = (const float*)d_in[6];
    float* out = (float*)d_out;

    char* w = (char*)d_ws;
    int* inv = (int*)w;        w += (size_t)BB*SCELLS*4;
    int* idx = (int*)w;        w += (size_t)BB*PB*KK*4;
    float* h = (float*)w;      w += (size_t)BB*PB*DD*4;
    float* bnMu = (float*)w;   w += (size_t)BB*64*4;
    float* bnScale = (float*)w; w += (size_t)BB*64*4;
    float* pSum = (float*)w;   w += (size_t)BB*32*64*4;
    float* pSq = (float*)w;    w += (size_t)BB*32*64*4;
    float* logits = (float*)w;                    // 98.3 MB, per-batch reuse
    // pV/pI alias logits: score+merge fully complete (stream-ordered) before
    // k_logits writes this region. 2*8*6000*4*4B*2 = 3.1 MB << 98.3 MB.
    float* pV = logits;
    int*   pI = (int*)(logits + (size_t)BB*NSEG*PB*KK);

    k_init_inv<<<dim3(BB*SCELLS/256), dim3(256), 0, stream>>>(inv);
    k_scatter_inv<<<dim3((BB*PB+255)/256), dim3(256), 0, stream>>>(coords, inv);
    k_score_topk<<<dim3(NPBLK, BB, NSEG), dim3(256), 0, stream>>>(pillars, points, pV, pI);
    k_merge<<<dim3((BB*PB+255)/256), dim3(256), 0, stream>>>(pV, pI, idx);
    for (int b = 0; b < BB; b++) {
        k_logits<<<dim3(NROWS/64, 4), dim3(256), 0, stream>>>(points, idx, memw, logits, b);
        k_mo<<<dim3(PB/12), dim3(256), 0, stream>>>(logits, memw, adaptw, h, b);
    }
    k_bn1<<<dim3(BB*32), dim3(256), 0, stream>>>(h, pSum, pSq);
    k_bn2<<<dim3(BB), dim3(64), 0, stream>>>(pSum, pSq, gamma, bnMu, bnScale);
    k_fill<<<dim3(SCELLS/256, BB), dim3(256), 0, stream>>>(inv, pillars, h, bnMu, bnScale, beta, out);
}